// Round 4
// baseline (180.724 us; speedup 1.0000x reference)
//
#include <hip/hip_runtime.h>
#include <cstddef>
#include <math.h>

#define NN 50000
#define DEG 16
#define NEG_SLOPE 0.2f

typedef __attribute__((ext_vector_type(8))) short bf16x8;
typedef __attribute__((ext_vector_type(4))) float f32x4;

__device__ inline unsigned short f2bf(float x) {
    unsigned u = __float_as_uint(x);
    return (unsigned short)((u + 0x7FFF + ((u >> 16) & 1)) >> 16);
}
__device__ inline float bf2f(unsigned short u) {
    return __uint_as_float(((unsigned)u) << 16);
}
__device__ inline unsigned pack_bf2(float lo, float hi) {
    return (unsigned)f2bf(lo) | ((unsigned)f2bf(hi) << 16);
}

// ---------------- W prep: Wt[c][k] (bf16) from W[k][c] (f32), 128 cols -----------
__global__ void wprep_k(const float* __restrict__ W, unsigned short* __restrict__ Wt,
                        int K, int s)
{
    int idx = blockIdx.x * 256 + threadIdx.x;      // idx = c*K + k
    if (idx >= (128 << s)) return;
    int c = idx >> s, k = idx & (K - 1);
    Wt[idx] = f2bf(W[(size_t)k * 128 + c]);
}

// ---------------- MFMA GEMM [N,K] x [K,128] -> feat_bf16 + el/er (H heads) -------
// Fully register-resident: no LDS, no barriers. 4 independent waves/block,
// each wave owns 16 rows x 128 cols (8 col-frags). A loaded f32 from global,
// split hi/lo bf16 in-register: A*W = (Ah+Al)*bf16(W), W-side rel err ~2^-9.
// Frag maps (HW-verified rounds 3): A lane->row=l&15, k=(l>>4)*8+j;
// B lane->col=cf*16+(l&15), k=(l>>4)*8+j; C/D row=(l>>4)*4+reg, col=cf*16+(l&15).
template<int K, int H>
__launch_bounds__(256)
__global__ void gemm_mfma_k(const float* __restrict__ A,
                            const unsigned short* __restrict__ Wt,
                            const float* __restrict__ al, const float* __restrict__ ar,
                            unsigned short* __restrict__ feat,
                            float* __restrict__ el, float* __restrict__ er)
{
    const int tid = threadIdx.x;
    const int w = tid >> 6, l = tid & 63;
    const int lr = l & 15, lq = l >> 4;
    const int row0 = blockIdx.x * 64 + w * 16;
    int arow = row0 + lr; if (arow > NN - 1) arow = NN - 1;
    const float* Arow = A + (size_t)arow * K + lq * 8;

    f32x4 acc[8];
#pragma unroll
    for (int cf = 0; cf < 8; cf++) acc[cf] = (f32x4){0.f, 0.f, 0.f, 0.f};

#pragma unroll 2
    for (int kc = 0; kc < K; kc += 32) {
        float4 v0 = *(const float4*)(Arow + kc);
        float4 v1 = *(const float4*)(Arow + kc + 4);
        float xs[8] = {v0.x, v0.y, v0.z, v0.w, v1.x, v1.y, v1.z, v1.w};
        short hs[8], ls[8];
#pragma unroll
        for (int i = 0; i < 8; i++) {
            unsigned short h = f2bf(xs[i]);
            hs[i] = (short)h;
            ls[i] = (short)f2bf(xs[i] - bf2f(h));
        }
        bf16x8 ah = {hs[0], hs[1], hs[2], hs[3], hs[4], hs[5], hs[6], hs[7]};
        bf16x8 alo = {ls[0], ls[1], ls[2], ls[3], ls[4], ls[5], ls[6], ls[7]};
#pragma unroll
        for (int cf = 0; cf < 8; cf++) {
            bf16x8 b = *(const bf16x8*)(Wt + (size_t)(cf * 16 + lr) * K + kc + lq * 8);
            acc[cf] = __builtin_amdgcn_mfma_f32_16x16x32_bf16(ah, b, acc[cf], 0, 0, 0);
            acc[cf] = __builtin_amdgcn_mfma_f32_16x16x32_bf16(alo, b, acc[cf], 0, 0, 0);
        }
    }

    // ---- epilogue: feat bf16 store ----
#pragma unroll
    for (int reg = 0; reg < 4; reg++) {
        const int r = row0 + lq * 4 + reg;
        if (r < NN) {
#pragma unroll
            for (int cf = 0; cf < 8; cf++)
                feat[(size_t)r * 128 + cf * 16 + lr] = f2bf(acc[cf][reg]);
        }
    }

    // ---- el/er ----
    if (H == 4) {
        float pe[4][4], pr[4][4];   // [reg][head]; head = cf>>1
#pragma unroll
        for (int reg = 0; reg < 4; reg++)
#pragma unroll
            for (int h = 0; h < 4; h++) {
                float a0 = al[(2 * h) * 16 + lr], a1 = al[(2 * h + 1) * 16 + lr];
                float r0 = ar[(2 * h) * 16 + lr], r1 = ar[(2 * h + 1) * 16 + lr];
                pe[reg][h] = acc[2 * h][reg] * a0 + acc[2 * h + 1][reg] * a1;
                pr[reg][h] = acc[2 * h][reg] * r0 + acc[2 * h + 1][reg] * r1;
            }
#pragma unroll
        for (int m = 1; m < 16; m <<= 1)
#pragma unroll
            for (int reg = 0; reg < 4; reg++)
#pragma unroll
                for (int h = 0; h < 4; h++) {
                    pe[reg][h] += __shfl_xor(pe[reg][h], m);
                    pr[reg][h] += __shfl_xor(pr[reg][h], m);
                }
        if (lr == 0) {
#pragma unroll
            for (int reg = 0; reg < 4; reg++) {
                const int r = row0 + lq * 4 + reg;
                if (r < NN) {
#pragma unroll
                    for (int h = 0; h < 4; h++) {
                        el[r * 4 + h] = pe[reg][h];
                        er[r * 4 + h] = pr[reg][h];
                    }
                }
            }
        }
    } else {
        float pe[4], pr[4];
#pragma unroll
        for (int reg = 0; reg < 4; reg++) {
            float se = 0.f, sr = 0.f;
#pragma unroll
            for (int cf = 0; cf < 8; cf++) {
                se += acc[cf][reg] * al[cf * 16 + lr];
                sr += acc[cf][reg] * ar[cf * 16 + lr];
            }
            pe[reg] = se; pr[reg] = sr;
        }
#pragma unroll
        for (int m = 1; m < 16; m <<= 1)
#pragma unroll
            for (int reg = 0; reg < 4; reg++) {
                pe[reg] += __shfl_xor(pe[reg], m);
                pr[reg] += __shfl_xor(pr[reg], m);
            }
        if (lr == 0) {
#pragma unroll
            for (int reg = 0; reg < 4; reg++) {
                const int r = row0 + lq * 4 + reg;
                if (r < NN) { el[r] = pe[reg]; er[r] = pr[reg]; }
            }
        }
    }
}

// ---------------- edge softmax + aggregate, 128 cols bf16 gather, H heads --------
template<int H>
__launch_bounds__(256)
__global__ void agg128_k(const unsigned short* __restrict__ feat, const float* __restrict__ el,
                         const float* __restrict__ er, const int* __restrict__ src,
                         const float* __restrict__ bias, float* __restrict__ out, int do_relu)
{
    __shared__ float s_alpha[4][16 * H];
    __shared__ int s_src[4][DEG];
    const int tid = threadIdx.x;
    const int w = tid >> 6, lane = tid & 63;
    const int node = blockIdx.x * 4 + w;
    const int j = lane & 15;
    const int h = lane >> 4;

    int s = src[node * DEG + j];
    float e;
    if (H == 4) e = el[s * 4 + h] + er[node * 4 + h];
    else        e = el[s] + er[node];
    e = (e > 0.f) ? e : NEG_SLOPE * e;
    float mx = e;
#pragma unroll
    for (int d = 1; d < 16; d <<= 1) mx = fmaxf(mx, __shfl_xor(mx, d));
    float ex = expf(e - mx);
    float den = ex;
#pragma unroll
    for (int d = 1; d < 16; d <<= 1) den += __shfl_xor(den, d);
    float alpha = ex / den;
    if (H == 4) s_alpha[w][h * 16 + j] = alpha;
    else if (lane < 16) s_alpha[w][j] = alpha;
    if (lane < 16) s_src[w][j] = s;
    __syncthreads();

    const int half = lane >> 5;
    const int li = lane & 31;
    const int hd = li >> 3;
    float acc[4] = {0.f, 0.f, 0.f, 0.f};
#pragma unroll
    for (int jj2 = 0; jj2 < 8; jj2++) {
        int jj = jj2 * 2 + half;
        int sj = s_src[w][jj];
        float a = (H == 4) ? s_alpha[w][hd * 16 + jj] : s_alpha[w][jj];
        ushort4 v = *(const ushort4*)(feat + (size_t)sj * 128 + 4 * li);
        acc[0] += a * bf2f(v.x);
        acc[1] += a * bf2f(v.y);
        acc[2] += a * bf2f(v.z);
        acc[3] += a * bf2f(v.w);
    }
#pragma unroll
    for (int q = 0; q < 4; q++) acc[q] += __shfl_xor(acc[q], 32);
    if (half == 0) {
        float4 o;
        o.x = acc[0] + bias[4 * li + 0];
        o.y = acc[1] + bias[4 * li + 1];
        o.z = acc[2] + bias[4 * li + 2];
        o.w = acc[3] + bias[4 * li + 3];
        if (do_relu) {
            o.x = fmaxf(o.x, 0.f); o.y = fmaxf(o.y, 0.f);
            o.z = fmaxf(o.z, 0.f); o.w = fmaxf(o.w, 0.f);
        }
        *(float4*)&out[(size_t)node * 128 + 4 * li] = o;
    }
}

// ---------------- GEMM [N,128] x [128,40] -> feat2_bf16 + el2/er2 (1 head) -------
__launch_bounds__(256)
__global__ void gemm40_k(const float* __restrict__ A, const float* __restrict__ W,
                         const float* __restrict__ al, const float* __restrict__ ar,
                         unsigned short* __restrict__ feat, float* __restrict__ el,
                         float* __restrict__ er)
{
    __shared__ float As[32][132];
    __shared__ float Ws[128 * 40];
    const int tid = threadIdx.x;
    const int tx = tid & 31;       // lanes tx<20 own cols {2tx, 2tx+1}
    const int ty = tid >> 5;       // rows ty*4 .. ty*4+3 (32 rows/block)
    const int row0 = blockIdx.x * 32;

    {
        const float4* s4 = (const float4*)W;
        float4* d4 = (float4*)Ws;
#pragma unroll
        for (int q = 0; q < 5; q++) d4[tid + 256 * q] = s4[tid + 256 * q];
    }
    {
        int r = tid >> 3;
        int gr = row0 + r; if (gr > NN - 1) gr = NN - 1;
        const float4* s4 = (const float4*)(A + (size_t)gr * 128);
#pragma unroll
        for (int q = 0; q < 4; q++) {
            float4 v = s4[(tid & 7) + 8 * q];
            *(float4*)&As[r][4 * ((tid & 7) + 8 * q)] = v;
        }
    }
    __syncthreads();

    const int ctx = (tx < 20) ? tx : 19;
    const float2* Wf2 = (const float2*)Ws;
    float acc[4][2] = {};
#pragma unroll 4
    for (int k = 0; k < 128; k++) {
        float2 wv = Wf2[k * 20 + ctx];
#pragma unroll
        for (int i = 0; i < 4; i++) {
            float a = As[ty * 4 + i][k];
            acc[i][0] += a * wv.x;
            acc[i][1] += a * wv.y;
        }
    }
    float pel[4], per[4];
#pragma unroll
    for (int i = 0; i < 4; i++) {
        float vl = 0.f, vr = 0.f;
        if (tx < 20) {
            vl = acc[i][0] * al[2 * ctx] + acc[i][1] * al[2 * ctx + 1];
            vr = acc[i][0] * ar[2 * ctx] + acc[i][1] * ar[2 * ctx + 1];
        }
        pel[i] = vl; per[i] = vr;
    }
#pragma unroll
    for (int m = 1; m < 32; m <<= 1) {
#pragma unroll
        for (int i = 0; i < 4; i++) {
            pel[i] += __shfl_xor(pel[i], m);
            per[i] += __shfl_xor(per[i], m);
        }
    }
#pragma unroll
    for (int i = 0; i < 4; i++) {
        int r = row0 + ty * 4 + i;
        if (r < NN) {
            if (tx < 20) *(unsigned*)&feat[(size_t)r * 40 + 2 * tx] = pack_bf2(acc[i][0], acc[i][1]);
            if (tx == 0) { el[r] = pel[i]; er[r] = per[i]; }
        }
    }
}

// ---------------- edge softmax + aggregate 40 cols bf16 + log_softmax ------------
// 2 nodes per wave (one per 32-lane half); lanes li<20 own cols {2li,2li+1}.
__launch_bounds__(256)
__global__ void agg40_ls_k(const unsigned short* __restrict__ feat, const float* __restrict__ el,
                           const float* __restrict__ er, const int* __restrict__ src,
                           const float* __restrict__ bias, float* __restrict__ out)
{
    __shared__ float s_alpha[8][DEG];
    __shared__ int s_src[8][DEG];
    const int tid = threadIdx.x;
    const int w = tid >> 6, lane = tid & 63;
    const int half = lane >> 5, li = lane & 31;
    const int slot = w * 2 + half;
    const int node = blockIdx.x * 8 + slot;
    const int j = li & 15;

    int s = src[node * DEG + j];
    float e = el[s] + er[node];
    e = (e > 0.f) ? e : NEG_SLOPE * e;
    float mx = e;
#pragma unroll
    for (int d = 1; d < 16; d <<= 1) mx = fmaxf(mx, __shfl_xor(mx, d));
    float ex = expf(e - mx);
    float den = ex;
#pragma unroll
    for (int d = 1; d < 16; d <<= 1) den += __shfl_xor(den, d);
    if (li < 16) { s_alpha[slot][j] = ex / den; s_src[slot][j] = s; }
    __syncthreads();

    float acc0 = 0.f, acc1 = 0.f;
    if (li < 20) {
#pragma unroll
        for (int jj = 0; jj < DEG; jj++) {
            int sj = s_src[slot][jj];
            float a = s_alpha[slot][jj];
            unsigned v = *(const unsigned*)(feat + (size_t)sj * 40 + 2 * li);
            acc0 += a * bf2f((unsigned short)(v & 0xFFFF));
            acc1 += a * bf2f((unsigned short)(v >> 16));
        }
    }
    float v0 = acc0 + bias[2 * li], v1 = acc1 + bias[2 * li + 1];
    float m2 = (li < 20) ? fmaxf(v0, v1) : -INFINITY;
#pragma unroll
    for (int d = 1; d < 32; d <<= 1) m2 = fmaxf(m2, __shfl_xor(m2, d));
    float pe = (li < 20) ? (expf(v0 - m2) + expf(v1 - m2)) : 0.f;
    float se = pe;
#pragma unroll
    for (int d = 1; d < 32; d <<= 1) se += __shfl_xor(se, d);
    if (li < 20) {
        float ls = m2 + logf(se);
        out[(size_t)node * 40 + 2 * li]     = v0 - ls;
        out[(size_t)node * 40 + 2 * li + 1] = v1 - ls;
    }
}

extern "C" void kernel_launch(void* const* d_in, const int* in_sizes, int n_in,
                              void* d_out, int out_size, void* d_ws, size_t ws_size,
                              hipStream_t stream)
{
    const float* features = (const float*)d_in[0];
    const int*   src      = (const int*)d_in[1];
    // d_in[2] = dst: structurally repeat(arange(N),16) -> unused
    const float* W1  = (const float*)d_in[3];
    const float* al1 = (const float*)d_in[4];
    const float* ar1 = (const float*)d_in[5];
    const float* b1  = (const float*)d_in[6];
    const float* Wh  = (const float*)d_in[7];
    const float* alh = (const float*)d_in[8];
    const float* arh = (const float*)d_in[9];
    const float* bh  = (const float*)d_in[10];
    const float* W2  = (const float*)d_in[11];
    const float* al2 = (const float*)d_in[12];
    const float* ar2 = (const float*)d_in[13];
    const float* b2  = (const float*)d_in[14];
    float* out = (float*)d_out;

    float* ws = (float*)d_ws;
    unsigned short* featb = (unsigned short*)ws;   // N*128 bf16 (= N*64 floats)
    float* hb   = ws + (size_t)NN * 64;            // N*128 f32
    float* el1  = hb  + (size_t)NN * 128;          // N*4
    float* er1  = el1 + (size_t)NN * 4;            // N*4
    float* elA  = er1 + (size_t)NN * 4;            // N
    float* erA  = elA + NN;                        // N
    unsigned short* f40b = (unsigned short*)(erA + NN);   // N*40 bf16 (= N*20 floats)
    unsigned short* Wt1  = (unsigned short*)(erA + NN + (size_t)NN * 20);  // 128*256
    unsigned short* Wth  = Wt1 + 128 * 256;                                // 128*128

    dim3 blk(256);
    // W prep (transpose + bf16)
    wprep_k<<<128, blk, 0, stream>>>(W1, Wt1, 256, 8);
    wprep_k<<<64,  blk, 0, stream>>>(Wh, Wth, 128, 7);
    // layer 1: GATConv(256 -> 32x4 heads)
    gemm_mfma_k<256, 4><<<782, blk, 0, stream>>>(features, Wt1, al1, ar1, featb, el1, er1);
    agg128_k<4><<<12500, blk, 0, stream>>>(featb, el1, er1, src, b1, hb, 1);
    // hidden: GATConv(128 -> 128, 1 head)
    gemm_mfma_k<128, 1><<<782, blk, 0, stream>>>(hb, Wth, alh, arh, featb, elA, erA);
    agg128_k<1><<<12500, blk, 0, stream>>>(featb, elA, erA, src, bh, hb, 1);
    // layer 2: GATConv(128 -> 40, 1 head) + log_softmax
    gemm40_k<<<1563, blk, 0, stream>>>(hb, W2, al2, ar2, f40b, elA, erA);
    agg40_ls_k<<<6250, blk, 0, stream>>>(f40b, elA, erA, src, b2, out);
}

// Round 5
// 177.671 us; speedup vs baseline: 1.0172x; 1.0172x over previous
//
#include <hip/hip_runtime.h>
#include <cstddef>
#include <math.h>

#define NN 50000
#define DEG 16
#define NEG_SLOPE 0.2f

typedef __attribute__((ext_vector_type(8))) short bf16x8;
typedef __attribute__((ext_vector_type(4))) float f32x4;

__device__ inline unsigned short f2bf(float x) {
    unsigned u = __float_as_uint(x);
    return (unsigned short)((u + 0x7FFF + ((u >> 16) & 1)) >> 16);
}
__device__ inline float bf2f(unsigned short u) {
    return __uint_as_float(((unsigned)u) << 16);
}
__device__ inline unsigned pack_bf2(float lo, float hi) {
    return (unsigned)f2bf(lo) | ((unsigned)f2bf(hi) << 16);
}

// ---------------- W prep: Wt[c][k] (bf16) from W[k][c] (f32), 128 cols -----------
__global__ void wprep_k(const float* __restrict__ W, unsigned short* __restrict__ Wt,
                        int K, int s)
{
    int idx = blockIdx.x * 256 + threadIdx.x;      // idx = c*K + k
    if (idx >= (128 << s)) return;
    int c = idx >> s, k = idx & (K - 1);
    Wt[idx] = f2bf(W[(size_t)k * 128 + c]);
}

// ---------------- MFMA GEMM [N,K] x [K,128] -> feat_bf16 + el/er (H heads) -------
// No LDS in main loop, no barriers in main loop. 4 waves/block; wave tile =
// 16 rows x 64 cols (4 col-frags): w>>1 picks row half, w&1 picks col half.
// Grid = N/32 (2x round-4) for latency-hiding occupancy (target ~24 waves/CU).
// Precision: A*W = (Ah+Al)*bf16(W), hi/lo split in-register.
// Frag maps (HW-verified rounds 3-4): A lane->row=l&15, k=(l>>4)*8+j;
// B lane->col=cf*16+(l&15), k=(l>>4)*8+j; C/D row=(l>>4)*4+reg, col=cf*16+(l&15).
template<int K, int H>
__launch_bounds__(256)
__global__ void gemm_mfma_k(const float* __restrict__ A,
                            const unsigned short* __restrict__ Wt,
                            const float* __restrict__ al, const float* __restrict__ ar,
                            unsigned short* __restrict__ feat,
                            float* __restrict__ el, float* __restrict__ er)
{
    __shared__ float redE[4][16];     // H==1 epilogue-only cross-wave reduce
    __shared__ float redR[4][16];
    const int tid = threadIdx.x;
    const int w = tid >> 6, l = tid & 63;
    const int lr = l & 15, lq = l >> 4;
    const int rw = w >> 1, cw = w & 1;
    const int row0 = blockIdx.x * 32 + rw * 16;
    const int col0 = cw * 64;
    int arow = row0 + lr; if (arow > NN - 1) arow = NN - 1;
    const float* Arow = A + (size_t)arow * K + lq * 8;

    f32x4 acc[4];
#pragma unroll
    for (int cf = 0; cf < 4; cf++) acc[cf] = (f32x4){0.f, 0.f, 0.f, 0.f};

#pragma unroll 2
    for (int kc = 0; kc < K; kc += 32) {
        float4 v0 = *(const float4*)(Arow + kc);
        float4 v1 = *(const float4*)(Arow + kc + 4);
        float xs[8] = {v0.x, v0.y, v0.z, v0.w, v1.x, v1.y, v1.z, v1.w};
        short hs[8], ls[8];
#pragma unroll
        for (int i = 0; i < 8; i++) {
            unsigned short h = f2bf(xs[i]);
            hs[i] = (short)h;
            ls[i] = (short)f2bf(xs[i] - bf2f(h));
        }
        bf16x8 ah = {hs[0], hs[1], hs[2], hs[3], hs[4], hs[5], hs[6], hs[7]};
        bf16x8 alo = {ls[0], ls[1], ls[2], ls[3], ls[4], ls[5], ls[6], ls[7]};
#pragma unroll
        for (int cf = 0; cf < 4; cf++) {
            bf16x8 b = *(const bf16x8*)(Wt + (size_t)(col0 + cf * 16 + lr) * K + kc + lq * 8);
            acc[cf] = __builtin_amdgcn_mfma_f32_16x16x32_bf16(ah, b, acc[cf], 0, 0, 0);
            acc[cf] = __builtin_amdgcn_mfma_f32_16x16x32_bf16(alo, b, acc[cf], 0, 0, 0);
        }
    }

    // ---- epilogue: feat bf16 store ----
#pragma unroll
    for (int reg = 0; reg < 4; reg++) {
        const int r = row0 + lq * 4 + reg;
        if (r < NN) {
#pragma unroll
            for (int cf = 0; cf < 4; cf++)
                feat[(size_t)r * 128 + col0 + cf * 16 + lr] = f2bf(acc[cf][reg]);
        }
    }

    // ---- el/er ----
    if (H == 4) {
        // wave owns heads {cw*2, cw*2+1}: head hp pairs frags {2hp, 2hp+1}
        float pe[4][2], pr[4][2];
#pragma unroll
        for (int reg = 0; reg < 4; reg++)
#pragma unroll
            for (int hp = 0; hp < 2; hp++) {
                float a0 = al[col0 + (2 * hp) * 16 + lr], a1 = al[col0 + (2 * hp + 1) * 16 + lr];
                float r0 = ar[col0 + (2 * hp) * 16 + lr], r1 = ar[col0 + (2 * hp + 1) * 16 + lr];
                pe[reg][hp] = acc[2 * hp][reg] * a0 + acc[2 * hp + 1][reg] * a1;
                pr[reg][hp] = acc[2 * hp][reg] * r0 + acc[2 * hp + 1][reg] * r1;
            }
#pragma unroll
        for (int m = 1; m < 16; m <<= 1)
#pragma unroll
            for (int reg = 0; reg < 4; reg++)
#pragma unroll
                for (int hp = 0; hp < 2; hp++) {
                    pe[reg][hp] += __shfl_xor(pe[reg][hp], m);
                    pr[reg][hp] += __shfl_xor(pr[reg][hp], m);
                }
        if (lr == 0) {
#pragma unroll
            for (int reg = 0; reg < 4; reg++) {
                const int r = row0 + lq * 4 + reg;
                if (r < NN) {
#pragma unroll
                    for (int hp = 0; hp < 2; hp++) {
                        el[r * 4 + cw * 2 + hp] = pe[reg][hp];
                        er[r * 4 + cw * 2 + hp] = pr[reg][hp];
                    }
                }
            }
        }
    } else {
        float pe[4], pr[4];
#pragma unroll
        for (int reg = 0; reg < 4; reg++) {
            float se = 0.f, sr = 0.f;
#pragma unroll
            for (int cf = 0; cf < 4; cf++) {
                se += acc[cf][reg] * al[col0 + cf * 16 + lr];
                sr += acc[cf][reg] * ar[col0 + cf * 16 + lr];
            }
            pe[reg] = se; pr[reg] = sr;
        }
#pragma unroll
        for (int m = 1; m < 16; m <<= 1)
#pragma unroll
            for (int reg = 0; reg < 4; reg++) {
                pe[reg] += __shfl_xor(pe[reg], m);
                pr[reg] += __shfl_xor(pr[reg], m);
            }
        if (lr == 0) {
#pragma unroll
            for (int reg = 0; reg < 4; reg++) {
                redE[w][lq * 4 + reg] = pe[reg];
                redR[w][lq * 4 + reg] = pr[reg];
            }
        }
        __syncthreads();
        if (tid < 32) {
            const int half = tid >> 4, idx = tid & 15;
            const int r = blockIdx.x * 32 + half * 16 + idx;
            if (r < NN) {
                el[r] = redE[half * 2][idx] + redE[half * 2 + 1][idx];
                er[r] = redR[half * 2][idx] + redR[half * 2 + 1][idx];
            }
        }
    }
}

// ---------------- edge softmax + aggregate, 128 cols bf16 gather, H heads --------
template<int H>
__launch_bounds__(256)
__global__ void agg128_k(const unsigned short* __restrict__ feat, const float* __restrict__ el,
                         const float* __restrict__ er, const int* __restrict__ src,
                         const float* __restrict__ bias, float* __restrict__ out, int do_relu)
{
    __shared__ float s_alpha[4][16 * H];
    __shared__ int s_src[4][DEG];
    const int tid = threadIdx.x;
    const int w = tid >> 6, lane = tid & 63;
    const int node = blockIdx.x * 4 + w;
    const int j = lane & 15;
    const int h = lane >> 4;

    int s = src[node * DEG + j];
    float e;
    if (H == 4) e = el[s * 4 + h] + er[node * 4 + h];
    else        e = el[s] + er[node];
    e = (e > 0.f) ? e : NEG_SLOPE * e;
    float mx = e;
#pragma unroll
    for (int d = 1; d < 16; d <<= 1) mx = fmaxf(mx, __shfl_xor(mx, d));
    float ex = expf(e - mx);
    float den = ex;
#pragma unroll
    for (int d = 1; d < 16; d <<= 1) den += __shfl_xor(den, d);
    float alpha = ex / den;
    if (H == 4) s_alpha[w][h * 16 + j] = alpha;
    else if (lane < 16) s_alpha[w][j] = alpha;
    if (lane < 16) s_src[w][j] = s;
    __syncthreads();

    const int half = lane >> 5;
    const int li = lane & 31;
    const int hd = li >> 3;
    float acc[4] = {0.f, 0.f, 0.f, 0.f};
#pragma unroll
    for (int jj2 = 0; jj2 < 8; jj2++) {
        int jj = jj2 * 2 + half;
        int sj = s_src[w][jj];
        float a = (H == 4) ? s_alpha[w][hd * 16 + jj] : s_alpha[w][jj];
        ushort4 v = *(const ushort4*)(feat + (size_t)sj * 128 + 4 * li);
        acc[0] += a * bf2f(v.x);
        acc[1] += a * bf2f(v.y);
        acc[2] += a * bf2f(v.z);
        acc[3] += a * bf2f(v.w);
    }
#pragma unroll
    for (int q = 0; q < 4; q++) acc[q] += __shfl_xor(acc[q], 32);
    if (half == 0) {
        float4 o;
        o.x = acc[0] + bias[4 * li + 0];
        o.y = acc[1] + bias[4 * li + 1];
        o.z = acc[2] + bias[4 * li + 2];
        o.w = acc[3] + bias[4 * li + 3];
        if (do_relu) {
            o.x = fmaxf(o.x, 0.f); o.y = fmaxf(o.y, 0.f);
            o.z = fmaxf(o.z, 0.f); o.w = fmaxf(o.w, 0.f);
        }
        *(float4*)&out[(size_t)node * 128 + 4 * li] = o;
    }
}

// ---------------- GEMM [N,128] x [128,40] -> feat2_bf16 + el2/er2 (1 head) -------
__launch_bounds__(256)
__global__ void gemm40_k(const float* __restrict__ A, const float* __restrict__ W,
                         const float* __restrict__ al, const float* __restrict__ ar,
                         unsigned short* __restrict__ feat, float* __restrict__ el,
                         float* __restrict__ er)
{
    __shared__ float As[32][132];
    __shared__ float Ws[128 * 40];
    const int tid = threadIdx.x;
    const int tx = tid & 31;       // lanes tx<20 own cols {2tx, 2tx+1}
    const int ty = tid >> 5;       // rows ty*4 .. ty*4+3 (32 rows/block)
    const int row0 = blockIdx.x * 32;

    {
        const float4* s4 = (const float4*)W;
        float4* d4 = (float4*)Ws;
#pragma unroll
        for (int q = 0; q < 5; q++) d4[tid + 256 * q] = s4[tid + 256 * q];
    }
    {
        int r = tid >> 3;
        int gr = row0 + r; if (gr > NN - 1) gr = NN - 1;
        const float4* s4 = (const float4*)(A + (size_t)gr * 128);
#pragma unroll
        for (int q = 0; q < 4; q++) {
            float4 v = s4[(tid & 7) + 8 * q];
            *(float4*)&As[r][4 * ((tid & 7) + 8 * q)] = v;
        }
    }
    __syncthreads();

    const int ctx = (tx < 20) ? tx : 19;
    const float2* Wf2 = (const float2*)Ws;
    float acc[4][2] = {};
#pragma unroll 4
    for (int k = 0; k < 128; k++) {
        float2 wv = Wf2[k * 20 + ctx];
#pragma unroll
        for (int i = 0; i < 4; i++) {
            float a = As[ty * 4 + i][k];
            acc[i][0] += a * wv.x;
            acc[i][1] += a * wv.y;
        }
    }
    float pel[4], per[4];
#pragma unroll
    for (int i = 0; i < 4; i++) {
        float vl = 0.f, vr = 0.f;
        if (tx < 20) {
            vl = acc[i][0] * al[2 * ctx] + acc[i][1] * al[2 * ctx + 1];
            vr = acc[i][0] * ar[2 * ctx] + acc[i][1] * ar[2 * ctx + 1];
        }
        pel[i] = vl; per[i] = vr;
    }
#pragma unroll
    for (int m = 1; m < 32; m <<= 1) {
#pragma unroll
        for (int i = 0; i < 4; i++) {
            pel[i] += __shfl_xor(pel[i], m);
            per[i] += __shfl_xor(per[i], m);
        }
    }
#pragma unroll
    for (int i = 0; i < 4; i++) {
        int r = row0 + ty * 4 + i;
        if (r < NN) {
            if (tx < 20) *(unsigned*)&feat[(size_t)r * 40 + 2 * tx] = pack_bf2(acc[i][0], acc[i][1]);
            if (tx == 0) { el[r] = pel[i]; er[r] = per[i]; }
        }
    }
}

// ---------------- edge softmax + aggregate 40 cols bf16 + log_softmax ------------
// 2 nodes per wave (one per 32-lane half); lanes li<20 own cols {2li,2li+1}.
__launch_bounds__(256)
__global__ void agg40_ls_k(const unsigned short* __restrict__ feat, const float* __restrict__ el,
                           const float* __restrict__ er, const int* __restrict__ src,
                           const float* __restrict__ bias, float* __restrict__ out)
{
    __shared__ float s_alpha[8][DEG];
    __shared__ int s_src[8][DEG];
    const int tid = threadIdx.x;
    const int w = tid >> 6, lane = tid & 63;
    const int half = lane >> 5, li = lane & 31;
    const int slot = w * 2 + half;
    const int node = blockIdx.x * 8 + slot;
    const int j = li & 15;

    int s = src[node * DEG + j];
    float e = el[s] + er[node];
    e = (e > 0.f) ? e : NEG_SLOPE * e;
    float mx = e;
#pragma unroll
    for (int d = 1; d < 16; d <<= 1) mx = fmaxf(mx, __shfl_xor(mx, d));
    float ex = expf(e - mx);
    float den = ex;
#pragma unroll
    for (int d = 1; d < 16; d <<= 1) den += __shfl_xor(den, d);
    if (li < 16) { s_alpha[slot][j] = ex / den; s_src[slot][j] = s; }
    __syncthreads();

    float acc0 = 0.f, acc1 = 0.f;
    if (li < 20) {
#pragma unroll
        for (int jj = 0; jj < DEG; jj++) {
            int sj = s_src[slot][jj];
            float a = s_alpha[slot][jj];
            unsigned v = *(const unsigned*)(feat + (size_t)sj * 40 + 2 * li);
            acc0 += a * bf2f((unsigned short)(v & 0xFFFF));
            acc1 += a * bf2f((unsigned short)(v >> 16));
        }
    }
    float v0 = acc0 + bias[2 * li], v1 = acc1 + bias[2 * li + 1];
    float m2 = (li < 20) ? fmaxf(v0, v1) : -INFINITY;
#pragma unroll
    for (int d = 1; d < 32; d <<= 1) m2 = fmaxf(m2, __shfl_xor(m2, d));
    float pe = (li < 20) ? (expf(v0 - m2) + expf(v1 - m2)) : 0.f;
    float se = pe;
#pragma unroll
    for (int d = 1; d < 32; d <<= 1) se += __shfl_xor(se, d);
    if (li < 20) {
        float ls = m2 + logf(se);
        out[(size_t)node * 40 + 2 * li]     = v0 - ls;
        out[(size_t)node * 40 + 2 * li + 1] = v1 - ls;
    }
}

extern "C" void kernel_launch(void* const* d_in, const int* in_sizes, int n_in,
                              void* d_out, int out_size, void* d_ws, size_t ws_size,
                              hipStream_t stream)
{
    const float* features = (const float*)d_in[0];
    const int*   src      = (const int*)d_in[1];
    // d_in[2] = dst: structurally repeat(arange(N),16) -> unused
    const float* W1  = (const float*)d_in[3];
    const float* al1 = (const float*)d_in[4];
    const float* ar1 = (const float*)d_in[5];
    const float* b1  = (const float*)d_in[6];
    const float* Wh  = (const float*)d_in[7];
    const float* alh = (const float*)d_in[8];
    const float* arh = (const float*)d_in[9];
    const float* bh  = (const float*)d_in[10];
    const float* W2  = (const float*)d_in[11];
    const float* al2 = (const float*)d_in[12];
    const float* ar2 = (const float*)d_in[13];
    const float* b2  = (const float*)d_in[14];
    float* out = (float*)d_out;

    float* ws = (float*)d_ws;
    unsigned short* featb = (unsigned short*)ws;   // N*128 bf16 (= N*64 floats)
    float* hb   = ws + (size_t)NN * 64;            // N*128 f32
    float* el1  = hb  + (size_t)NN * 128;          // N*4
    float* er1  = el1 + (size_t)NN * 4;            // N*4
    float* elA  = er1 + (size_t)NN * 4;            // N
    float* erA  = elA + NN;                        // N
    unsigned short* f40b = (unsigned short*)(erA + NN);   // N*40 bf16 (= N*20 floats)
    unsigned short* Wt1  = (unsigned short*)(erA + NN + (size_t)NN * 20);  // 128*256
    unsigned short* Wth  = Wt1 + 128 * 256;                                // 128*128

    dim3 blk(256);
    // W prep (transpose + bf16)
    wprep_k<<<128, blk, 0, stream>>>(W1, Wt1, 256, 8);
    wprep_k<<<64,  blk, 0, stream>>>(Wh, Wth, 128, 7);
    // layer 1: GATConv(256 -> 32x4 heads)
    gemm_mfma_k<256, 4><<<1563, blk, 0, stream>>>(features, Wt1, al1, ar1, featb, el1, er1);
    agg128_k<4><<<12500, blk, 0, stream>>>(featb, el1, er1, src, b1, hb, 1);
    // hidden: GATConv(128 -> 128, 1 head)
    gemm_mfma_k<128, 1><<<1563, blk, 0, stream>>>(hb, Wth, alh, arh, featb, elA, erA);
    agg128_k<1><<<12500, blk, 0, stream>>>(featb, elA, erA, src, bh, hb, 1);
    // layer 2: GATConv(128 -> 40, 1 head) + log_softmax
    gemm40_k<<<1563, blk, 0, stream>>>(hb, W2, al2, ar2, f40b, elA, erA);
    agg40_ls_k<<<6250, blk, 0, stream>>>(f40b, elA, erA, src, b2, out);
}